// Round 10
// baseline (427.973 us; speedup 1.0000x reference)
//
#include <hip/hip_runtime.h>
#include <stdint.h>

#define S_TOK 16384
#define M_DIM 512
#define E_EXP 16
#define D_OUT 256
#define H1D 500
#define H2D 500
#define H3D 1000

typedef float f32x4 __attribute__((ext_vector_type(4)));
typedef long lx2 __attribute__((ext_vector_type(2)));   // 16 B = two fp8 fragments
typedef int i32x2 __attribute__((ext_vector_type(2)));

template <bool HI>
__device__ __forceinline__ int pk8(float a, float b, int old) {
  return __builtin_amdgcn_cvt_pk_fp8_f32(a, b, old, HI);
}
__device__ __forceinline__ unsigned char f2fp8(float f) {
  return (unsigned char)(__builtin_amdgcn_cvt_pk_fp8_f32(f, 0.f, 0, false) & 0xff);
}

// async global->LDS, 16B per lane; LDS dest = wave-uniform base + lane*16
__device__ __forceinline__ void ld_lds16(const unsigned char* g, unsigned char* l) {
  __builtin_amdgcn_global_load_lds(
      (const __attribute__((address_space(1))) unsigned int*)(const void*)g,
      (__attribute__((address_space(3))) unsigned int*)(void*)l, 16, 0, 0);
}

struct TokenRec { int i1, i2; float g1, g2; };

// ---------------- router: lane-parallel experts, f64 accum, no global atomics ------
__global__ __launch_bounds__(256) void k_router(const float* __restrict__ x,
                                                const float* __restrict__ noise,
                                                const float* __restrict__ Wr,
                                                float* __restrict__ sel_out,
                                                float* __restrict__ sel_buf,
                                                TokenRec* __restrict__ te) {
  __shared__ float wr[E_EXP * 516];   // pad 516: 2-way LDS aliasing only (free)
  int t = threadIdx.x;
  for (int i = t; i < E_EXP * M_DIM; i += 256) {
    int e = i >> 9, m = i & 511;
    wr[e * 516 + m] = Wr[i];
  }
  __syncthreads();

  int wv = t >> 6, l = t & 63;
  int e = l & 15, tg = l >> 4;
  int s = blockIdx.x * 16 + wv * 4 + tg;

  const float* xr = x + (size_t)s * M_DIM;
  const float* wre = &wr[e * 516];
  double a0 = 0.0, a1 = 0.0, a2 = 0.0, a3 = 0.0;
#pragma unroll 4
  for (int m = 0; m < M_DIM; m += 4) {
    f32x4 xv = *(const f32x4*)(xr + m);
    f32x4 wv4 = *(const f32x4*)(wre + m);
    a0 += (double)xv.x * (double)wv4.x;
    a1 += (double)xv.y * (double)wv4.y;
    a2 += (double)xv.z * (double)wv4.z;
    a3 += (double)xv.w * (double)wv4.w;
  }
  double a = (a0 + a1) + (a2 + a3);
  a += (double)noise[(size_t)s * E_EXP + e];

  double mx = a;
#pragma unroll
  for (int off = 8; off >= 1; off >>= 1) { double o = __shfl_xor(mx, off, 64); mx = (o > mx) ? o : mx; }
  double p = exp(a - mx);
  double sum = p;
#pragma unroll
  for (int off = 8; off >= 1; off >>= 1) sum += __shfl_xor(sum, off, 64);
  sel_buf[(size_t)s * E_EXP + e] = (float)(p / sum);

  unsigned long long pb = __double_as_longlong(p);
  unsigned long long key = (pb & ~0xFFull) | (unsigned long long)(255 - e);
  unsigned long long k1 = key;
#pragma unroll
  for (int off = 8; off >= 1; off >>= 1) { unsigned long long o = __shfl_xor(k1, off, 64); k1 = (o > k1) ? o : k1; }
  int i1 = 255 - (int)(k1 & 0xFFull);
  unsigned long long key2 = (e == i1) ? 0ull : key;
  unsigned long long k2 = key2;
#pragma unroll
  for (int off = 8; off >= 1; off >>= 1) { unsigned long long o = __shfl_xor(k2, off, 64); k2 = (o > k2) ? o : k2; }
  int i2 = 255 - (int)(k2 & 0xFFull);

  double p1 = __shfl(p, tg * 16 + i1, 64);
  double p2 = __shfl(p, tg * 16 + i2, 64);

  sel_out[(size_t)s * E_EXP + e] = (e == i1 || e == i2) ? 1.f : 0.f;
  if (e == 0) {
    double inv = 1.0 / (p1 + p2);
    TokenRec r; r.i1 = i1; r.i2 = i2; r.g1 = (float)(p1 * inv); r.g2 = (float)(p2 * inv);
    te[s] = r;
  }
}

// ---------------- stats: per-block proxy partial sums + histogram ----------------
__global__ __launch_bounds__(256) void k_stats(const float* __restrict__ sel_buf,
                                               const TokenRec* __restrict__ te,
                                               float* __restrict__ partials) {  // [16][32]
  __shared__ float psum[256];
  __shared__ unsigned int hist[E_EXP];
  int t = threadIdx.x, b = blockIdx.x;
  if (t < E_EXP) hist[t] = 0u;
  __syncthreads();
  int e = t & 15, rg = t >> 4;
  int base = b * 1024;
  float acc = 0.f;
#pragma unroll 4
  for (int i = 0; i < 64; i++)
    acc += sel_buf[(size_t)(base + i * 16 + rg) * E_EXP + e];
  for (int i = t; i < 1024; i += 256) {
    TokenRec r = te[base + i];
    atomicAdd(&hist[r.i1], 1u);
    atomicAdd(&hist[r.i2], 1u);
  }
  psum[t] = acc;
  __syncthreads();
  if (t < E_EXP) {
    float v = 0.f;
#pragma unroll
    for (int rg2 = 0; rg2 < 16; rg2++) v += psum[rg2 * 16 + t];
    partials[b * 32 + t] = v;
    partials[b * 32 + 16 + t] = (float)hist[t];
  }
}

// ---------------- reduce partials -> counts/offsets + balance loss + cursor init ------
__global__ void k_prefix_loss(const float* __restrict__ partials,
                              unsigned int* __restrict__ counts,
                              unsigned int* __restrict__ offsets,
                              unsigned int* __restrict__ cursor,
                              float* __restrict__ out_loss) {
  __shared__ float pr[E_EXP];
  __shared__ unsigned int cn[E_EXP];
  int t = threadIdx.x;
  if (t < E_EXP) {
    float p = 0.f, c = 0.f;
    for (int b = 0; b < 16; b++) { p += partials[b * 32 + t]; c += partials[b * 32 + 16 + t]; }
    pr[t] = p; cn[t] = (unsigned int)(c + 0.5f);
    cursor[t] = 0u;
  }
  __syncthreads();
  if (t == 0) {
    unsigned int acc = 0; float ls = 0.f;
    for (int e = 0; e < E_EXP; e++) {
      counts[e] = cn[e];
      offsets[e] = acc;
      acc += cn[e];
      ls += pr[e] * (float)cn[e];
    }
    out_loss[0] = ls * ((float)E_EXP / ((float)S_TOK * (float)S_TOK));
    out_loss[1] = 0.f;
  }
}

// ---------------- listbuild: block-level reservation + inverse map ----------------
__global__ __launch_bounds__(256) void k_listbuild(const TokenRec* __restrict__ te,
                                                   const unsigned int* __restrict__ offsets,
                                                   unsigned int* __restrict__ cursor,
                                                   int* __restrict__ slot_token,
                                                   float* __restrict__ slot_gate,
                                                   int* __restrict__ tok_slot) {
  __shared__ unsigned int lhist[E_EXP];
  __shared__ unsigned int lbase[E_EXP];
  __shared__ unsigned int lcur[E_EXP];
  int t = threadIdx.x, b = blockIdx.x;
  int base = b * 1024;
  if (t < E_EXP) lhist[t] = 0u;
  __syncthreads();
  for (int i = t; i < 1024; i += 256) {
    TokenRec r = te[base + i];
    atomicAdd(&lhist[r.i1], 1u);
    atomicAdd(&lhist[r.i2], 1u);
  }
  __syncthreads();
  if (t < E_EXP) {
    lbase[t] = offsets[t] + atomicAdd(&cursor[t], lhist[t]);
    lcur[t] = 0u;
  }
  __syncthreads();
  for (int i = t; i < 1024; i += 256) {
    int s = base + i;
    TokenRec r = te[s];
    unsigned int p1 = atomicAdd(&lcur[r.i1], 1u);
    int sl1 = (int)(lbase[r.i1] + p1);
    slot_token[sl1] = s; slot_gate[sl1] = r.g1;
    unsigned int p2 = atomicAdd(&lcur[r.i2], 1u);
    int sl2 = (int)(lbase[r.i2] + p2);
    slot_token[sl2] = s; slot_gate[sl2] = r.g2;
    tok_slot[2 * s] = sl1;
    tok_slot[2 * s + 1] = sl2;
  }
}

// ---------------- gather x rows -> fp8 compact activations (k-interleaved) ----------
// within each 64-k block: byte = q*16 + h*8 + j  <->  k = h*32 + q*8 + j
__global__ __launch_bounds__(256) void k_gather(const float* __restrict__ x,
                                                const int* __restrict__ slot_token,
                                                unsigned char* __restrict__ xg) {
  int idx = blockIdx.x * 256 + threadIdx.x;   // 32768 * 64
  int row = idx >> 6, t6 = idx & 63;
  int blk = t6 >> 3, q = (t6 >> 1) & 3, h = t6 & 1;
  int tkn = slot_token[row];
  const float* xp = x + (size_t)tkn * M_DIM + blk * 64 + h * 32 + q * 8;
  f32x4 v0 = *(const f32x4*)xp;
  f32x4 v1 = *(const f32x4*)(xp + 4);
  int b0 = pk8<false>(v0.x, v0.y, 0); b0 = pk8<true>(v0.z, v0.w, b0);
  int b1 = pk8<false>(v1.x, v1.y, 0); b1 = pk8<true>(v1.z, v1.w, b1);
  i32x2 o; o.x = b0; o.y = b1;
  *(i32x2*)&xg[(size_t)row * 512 + blk * 64 + q * 16 + h * 8] = o;
}

// ---------------- fused weight convert (all 4 layers, one launch) --------------------
// f32 [E][Kr][Nr] -> fp8 transposed padded, k-interleaved [E][Np][Kp]
__global__ __launch_bounds__(256) void k_convw_all(const float* __restrict__ W1,
                                                   const float* __restrict__ W2,
                                                   const float* __restrict__ W3,
                                                   const float* __restrict__ W4,
                                                   unsigned char* __restrict__ D1,
                                                   unsigned char* __restrict__ D2,
                                                   unsigned char* __restrict__ D3,
                                                   unsigned char* __restrict__ D4) {
  __shared__ float tile[64][65];   // tile[k_local][n_local]
  int tb = blockIdx.x, e = blockIdx.y;
  const float* src; unsigned char* dst;
  int Kr, Nr, Kp, Np, kx, ny;
  if (tb < 64)        { src = W1; dst = D1; Kr = 512;  Nr = H1D; Kp = 512;  Np = 512;  kx = tb >> 3;  ny = tb & 7; }
  else if (tb < 128)  { tb -= 64;  src = W2; dst = D2; Kr = H1D; Nr = H2D; Kp = 512;  Np = 512;  kx = tb >> 3;  ny = tb & 7; }
  else if (tb < 256)  { tb -= 128; src = W3; dst = D3; Kr = H2D; Nr = H3D; Kp = 512;  Np = 1024; kx = tb >> 4;  ny = tb & 15; }
  else                { tb -= 256; src = W4; dst = D4; Kr = H3D; Nr = 256; Kp = 1024; Np = 256;  kx = tb >> 2;  ny = tb & 3; }
  int k0 = kx * 64, n0 = ny * 64;
  int t = threadIdx.x;
  int cx = t & 63, ry = t >> 6;
  const float* sp = src + (size_t)e * Kr * Nr;
#pragma unroll
  for (int i = 0; i < 16; i++) {
    int k = k0 + ry + i * 4, n = n0 + cx;
    float v = (k < Kr && n < Nr) ? sp[(size_t)k * Nr + n] : 0.f;
    tile[ry + i * 4][cx] = v;
  }
  __syncthreads();
  int nl = t >> 2, q = t & 3;
  int b0 = pk8<false>(tile[q * 8 + 0][nl], tile[q * 8 + 1][nl], 0);
  b0 = pk8<true>(tile[q * 8 + 2][nl], tile[q * 8 + 3][nl], b0);
  int b1 = pk8<false>(tile[q * 8 + 4][nl], tile[q * 8 + 5][nl], 0);
  b1 = pk8<true>(tile[q * 8 + 6][nl], tile[q * 8 + 7][nl], b1);
  int c0 = pk8<false>(tile[32 + q * 8 + 0][nl], tile[32 + q * 8 + 1][nl], 0);
  c0 = pk8<true>(tile[32 + q * 8 + 2][nl], tile[32 + q * 8 + 3][nl], c0);
  int c1 = pk8<false>(tile[32 + q * 8 + 4][nl], tile[32 + q * 8 + 5][nl], 0);
  c1 = pk8<true>(tile[32 + q * 8 + 6][nl], tile[32 + q * 8 + 7][nl], c1);
  uint4 pk; pk.x = (unsigned)b0; pk.y = (unsigned)b1; pk.z = (unsigned)c0; pk.w = (unsigned)c1;
  *(uint4*)&dst[(size_t)e * Np * Kp + (size_t)(n0 + nl) * Kp + k0 + q * 16] = pk;
}

// ---------------- grouped GEMM v6 (fp8, BK=64, K=512): 128x64 tile,
// B WEIGHTS IN REGISTERS (loop-invariant across m-tiles; 64 VGPR), A-only LDS dbuf.
// Per wave-step: 4 ds_read_b128 + 16 MFMA. One barrier/step, async A staging.
// mid: out = relu(in @ W^T + b) -> fp8 (pad cols zeroed)
__global__ __launch_bounds__(256, 3) void k_gemm_mid(const unsigned char* __restrict__ in,
                                                  const unsigned char* __restrict__ wt,
                                                  const float* __restrict__ bias,
                                                  unsigned char* __restrict__ out,
                                                  const unsigned int* __restrict__ offsets,
                                                  const unsigned int* __restrict__ counts,
                                                  int NP, int NREAL) {
  const int KP = 512, NK = 8;                  // all mid layers have K=512
  int e = blockIdx.z;
  int n_e = (int)counts[e];
  if (n_e == 0) return;
  int base = (int)offsets[e];
  int bn = blockIdx.y;
  __shared__ __align__(16) unsigned char As[2][128 * 64];  // 2 x 8 KB (A only)
  int t = threadIdx.x;
  int w = t >> 6, l = t & 63;
  int wm = w & 1, wn = w >> 1;
  int lr = l & 15, lq = l >> 4;
  int r_ = l >> 2, s_ = l & 3;
  int s2 = s_ ^ ((r_ >> 1) & 3);               // swizzled source segment (16 B units)
  int rsw = (lq ^ ((lr >> 1) & 3)) * 16;       // read-side swizzled byte offset
  int c0 = w * 2, c1 = w * 2 + 1;

  unsigned char* dA0[2] = {&As[0][c0 * 1024], &As[1][c0 * 1024]};
  unsigned char* dA1[2] = {&As[0][c1 * 1024], &As[1][c1 * 1024]};

  // preload B fragments for this (e, bn, wave) into registers: 2 nt x 8 ksteps x 16 B
  const unsigned char* bW = wt + (size_t)e * NP * KP;
  lx2 barr[2][NK];
#pragma unroll
  for (int nt = 0; nt < 2; nt++) {
    const unsigned char* brow = bW + (size_t)(bn * 64 + wn * 32 + nt * 16 + lr) * KP + lq * 16;
#pragma unroll
    for (int ks = 0; ks < NK; ks++)
      barr[nt][ks] = *(const lx2*)(brow + ks * 64);
  }

  for (int bm = blockIdx.x; bm * 128 < n_e; bm += gridDim.x) {
    int ra = bm * 128 + c0 * 16 + r_; ra = (ra < n_e) ? ra : (n_e - 1);
    int rb = bm * 128 + c1 * 16 + r_; rb = (rb < n_e) ? rb : (n_e - 1);
    const unsigned char* a0 = in + (size_t)(base + ra) * KP + s2 * 16;
    const unsigned char* a1 = in + (size_t)(base + rb) * KP + s2 * 16;
    f32x4 acc[4][2];
#pragma unroll
    for (int i = 0; i < 4; i++)
#pragma unroll
      for (int j = 0; j < 2; j++) acc[i][j] = (f32x4){0.f, 0.f, 0.f, 0.f};

    ld_lds16(a0, dA0[0]); ld_lds16(a1, dA1[0]);
    a0 += 64; a1 += 64;

#pragma unroll
    for (int ks = 0; ks < NK; ks++) {
      int cb = ks & 1, nb = cb ^ 1;
      __syncthreads();
      if (ks + 1 < NK) {
        ld_lds16(a0, dA0[nb]); ld_lds16(a1, dA1[nb]);
        a0 += 64; a1 += 64;
      }
      lx2 af[4];
#pragma unroll
      for (int mt = 0; mt < 4; mt++) af[mt] = *(const lx2*)&As[cb][(wm * 64 + mt * 16 + lr) * 64 + rsw];
#pragma unroll
      for (int mt = 0; mt < 4; mt++)
#pragma unroll
        for (int nt = 0; nt < 2; nt++) {
          acc[mt][nt] = __builtin_amdgcn_mfma_f32_16x16x32_fp8_fp8(af[mt].x, barr[nt][ks].x, acc[mt][nt], 0, 0, 0);
          acc[mt][nt] = __builtin_amdgcn_mfma_f32_16x16x32_fp8_fp8(af[mt].y, barr[nt][ks].y, acc[mt][nt], 0, 0, 0);
        }
    }

#pragma unroll
    for (int nt = 0; nt < 2; nt++) {
      int col = bn * 64 + wn * 32 + nt * 16 + lr;
      bool cok = col < NREAL;
      float bv = cok ? bias[(size_t)e * NREAL + col] : 0.f;
      int kl = col & 63;
      int pb = ((kl >> 3) & 3) * 16 + ((kl >> 5) & 1) * 8 + (kl & 7);
#pragma unroll
      for (int mt = 0; mt < 4; mt++)
#pragma unroll
        for (int reg = 0; reg < 4; reg++) {
          int r = bm * 128 + wm * 64 + mt * 16 + lq * 4 + reg;
          if (r < n_e) {
            float v = cok ? fmaxf(acc[mt][nt][reg] + bv, 0.f) : 0.f;
            out[(size_t)(base + r) * NP + bn * 64 + pb] = f2fp8(v);
          }
        }
    }
  }
}

// fin: 64x64 tile (2x2 waves of 32x32), K=1024, LDS dbuf both operands.
// eo[slot] = gate * (h3 @ W4 + b4); plain coalesced f32 stores
__global__ __launch_bounds__(256, 4) void k_gemm_fin(const unsigned char* __restrict__ in,
                                                  const unsigned char* __restrict__ wt,
                                                  const float* __restrict__ bias,
                                                  float* __restrict__ eo,
                                                  const unsigned int* __restrict__ offsets,
                                                  const unsigned int* __restrict__ counts,
                                                  const float* __restrict__ slot_gate) {
  const int KP = 1024, NP = 256;
  int e = blockIdx.z;
  int n_e = (int)counts[e];
  if (n_e == 0) return;
  int base = (int)offsets[e];
  int bn = blockIdx.y;
  __shared__ __align__(16) unsigned char As[2][64 * 64];   // 2 x 4 KB
  __shared__ __align__(16) unsigned char Bs[2][64 * 64];   // 2 x 4 KB
  int t = threadIdx.x;
  int w = t >> 6, l = t & 63;
  int wm = w & 1, wn = w >> 1;
  int lr = l & 15, lq = l >> 4;
  int r_ = l >> 2, s_ = l & 3;
  int s2 = s_ ^ ((r_ >> 1) & 3);
  int rsw = (lq ^ ((lr >> 1) & 3)) * 16;

  unsigned char* dA[2] = {&As[0][w * 1024], &As[1][w * 1024]};   // wave w stages rows w*16..+15
  unsigned char* dB[2] = {&Bs[0][w * 1024], &Bs[1][w * 1024]};

  const unsigned char* bW = wt + (size_t)e * NP * KP;
  const unsigned char* bsrc = bW + (size_t)(bn * 64 + w * 16 + r_) * KP + s2 * 16;
  int nk = KP >> 6;

  for (int bm = blockIdx.x; bm * 64 < n_e; bm += gridDim.x) {
    int ra = bm * 64 + w * 16 + r_; ra = (ra < n_e) ? ra : (n_e - 1);
    const unsigned char* a0 = in + (size_t)(base + ra) * KP + s2 * 16;
    const unsigned char* bq = bsrc;
    f32x4 acc[2][2];
#pragma unroll
    for (int i = 0; i < 2; i++)
#pragma unroll
      for (int j = 0; j < 2; j++) acc[i][j] = (f32x4){0.f, 0.f, 0.f, 0.f};

    ld_lds16(a0, dA[0]); ld_lds16(bq, dB[0]);
    a0 += 64; bq += 64;

    for (int ks = 0; ks < nk; ks++) {
      int cb = ks & 1, nb = cb ^ 1;
      __syncthreads();
      if (ks + 1 < nk) {
        ld_lds16(a0, dA[nb]); ld_lds16(bq, dB[nb]);
        a0 += 64; bq += 64;
      }
      lx2 af[2], bf[2];
#pragma unroll
      for (int mt = 0; mt < 2; mt++) af[mt] = *(const lx2*)&As[cb][(wm * 32 + mt * 16 + lr) * 64 + rsw];
#pragma unroll
      for (int nt = 0; nt < 2; nt++) bf[nt] = *(const lx2*)&Bs[cb][(wn * 32 + nt * 16 + lr) * 64 + rsw];
#pragma unroll
      for (int mt = 0; mt < 2; mt++)
#pragma unroll
        for (int nt = 0; nt < 2; nt++) {
          acc[mt][nt] = __builtin_amdgcn_mfma_f32_16x16x32_fp8_fp8(af[mt].x, bf[nt].x, acc[mt][nt], 0, 0, 0);
          acc[mt][nt] = __builtin_amdgcn_mfma_f32_16x16x32_fp8_fp8(af[mt].y, bf[nt].y, acc[mt][nt], 0, 0, 0);
        }
    }

#pragma unroll
    for (int mt = 0; mt < 2; mt++)
#pragma unroll
      for (int reg = 0; reg < 4; reg++) {
        int r = bm * 64 + wm * 32 + mt * 16 + lq * 4 + reg;
        if (r < n_e) {
          int gr = base + r;
          float g = slot_gate[gr];
#pragma unroll
          for (int nt = 0; nt < 2; nt++) {
            int col = bn * 64 + wn * 32 + nt * 16 + lr;
            eo[(size_t)gr * NP + col] = g * (acc[mt][nt][reg] + bias[(size_t)e * 256 + col]);
          }
        }
      }
  }
}

// ---------------- combine: out[s] = eo[sl1(s)] + eo[sl2(s)] ----------------
__global__ __launch_bounds__(256) void k_combine(const float* __restrict__ eo,
                                                 const int* __restrict__ tok_slot,
                                                 float* __restrict__ out) {
  int idx = blockIdx.x * 256 + threadIdx.x;
  int s = idx >> 6, q = idx & 63;
  int sl1 = tok_slot[2 * s], sl2 = tok_slot[2 * s + 1];
  f32x4 v1 = *(const f32x4*)&eo[(size_t)sl1 * D_OUT + q * 4];
  f32x4 v2 = *(const f32x4*)&eo[(size_t)sl2 * D_OUT + q * 4];
  *(f32x4*)&out[(size_t)s * D_OUT + q * 4] = v1 + v2;
}

extern "C" void kernel_launch(void* const* d_in, const int* in_sizes, int n_in,
                              void* d_out, int out_size, void* d_ws, size_t ws_size,
                              hipStream_t stream) {
  const float* x    = (const float*)d_in[0];
  const float* nois = (const float*)d_in[1];
  const float* Wr   = (const float*)d_in[2];
  const float* W1   = (const float*)d_in[3];
  const float* b1   = (const float*)d_in[4];
  const float* W2   = (const float*)d_in[5];
  const float* b2   = (const float*)d_in[6];
  const float* W3   = (const float*)d_in[7];
  const float* b3   = (const float*)d_in[8];
  const float* W4   = (const float*)d_in[9];
  const float* b4   = (const float*)d_in[10];
  float* out = (float*)d_out;

  char* w = (char*)d_ws;
  unsigned char* actA = (unsigned char*)(w + 0);          // 32768*1024 fp8 = 33554432 B
  unsigned char* actB = (unsigned char*)(w + 33554432);   // 32768*512 fp8  = 16777216 B
  unsigned char* Wt1  = (unsigned char*)(w + 50331648);   // 16*512*512   = 4 MB
  unsigned char* Wt2  = (unsigned char*)(w + 54525952);   // 4 MB
  unsigned char* Wt3  = (unsigned char*)(w + 58720256);   // 16*1024*512  = 8 MB
  unsigned char* Wt4  = (unsigned char*)(w + 67108864);   // 16*256*1024  = 4 MB
  float*         eo   = (float*)(w + 71303168);           // 32768*256 f32 = 33554432 B
  int*           slot_token = (int*)(w + 104857600);      // 131072 B
  float*         slot_gate  = (float*)(w + 104988672);    // 131072 B
  TokenRec*      te         = (TokenRec*)(w + 105119744); // 262144 B
  unsigned int*  counts  = (unsigned int*)(w + 105381888);
  unsigned int*  cursor  = (unsigned int*)(w + 105381952);
  unsigned int*  offsets = (unsigned int*)(w + 105382016);
  int*           tok_slot = (int*)(w + 105382080);        // 131072 B
  // transient overlays on actA (dead before L1 GEMM writes actA)
  float*         sel_buf  = (float*)(w + 0);              // 1 MB
  float*         partials = (float*)(w + 1048576);        // 2 KB

  float* sel_out  = out + (size_t)S_TOK * D_OUT;
  float* loss_out = out + (size_t)S_TOK * D_OUT + (size_t)S_TOK * E_EXP;

  // weight conversion depends only on inputs — single fused launch
  k_convw_all<<<dim3(320, E_EXP), dim3(256), 0, stream>>>(W1, W2, W3, W4, Wt1, Wt2, Wt3, Wt4);

  k_router<<<dim3(S_TOK / 16), dim3(256), 0, stream>>>(x, nois, Wr, sel_out, sel_buf, te);
  k_stats<<<dim3(16), dim3(256), 0, stream>>>(sel_buf, te, partials);
  k_prefix_loss<<<dim3(1), dim3(64), 0, stream>>>(partials, counts, offsets, cursor, loss_out);
  k_listbuild<<<dim3(16), dim3(256), 0, stream>>>(te, offsets, cursor, slot_token, slot_gate, tok_slot);
  k_gather<<<dim3((2 * S_TOK * 64) / 256), dim3(256), 0, stream>>>(x, slot_token, actB);

  // Layer 1: [*,512] @ [512,500] -> relu -> actA (stride 512)
  k_gemm_mid<<<dim3(8, 8, E_EXP), dim3(256), 0, stream>>>(actB, Wt1, b1, actA, offsets, counts, 512, H1D);
  // Layer 2: [*,500] @ [500,500] -> relu -> actB (stride 512)
  k_gemm_mid<<<dim3(8, 8, E_EXP), dim3(256), 0, stream>>>(actA, Wt2, b2, actB, offsets, counts, 512, H2D);
  // Layer 3: [*,500] @ [500,1000] -> relu -> actA (stride 1024)
  k_gemm_mid<<<dim3(8, 16, E_EXP), dim3(256), 0, stream>>>(actB, Wt3, b3, actA, offsets, counts, 1024, H3D);
  // Layer 4: [*,1000] @ [1000,256] -> eo[slot] = gate*(h3@W4+b4)   (64x64 tiles)
  k_gemm_fin<<<dim3(32, 4, E_EXP), dim3(256), 0, stream>>>(actA, Wt4, b4, eo, offsets, counts, slot_gate);
  // Combine: out[s] = eo[sl1] + eo[sl2]
  k_combine<<<dim3(S_TOK * 64 / 256), dim3(256), 0, stream>>>(eo, tok_slot, out);

  (void)in_sizes; (void)n_in; (void)out_size; (void)ws_size;
}